// Round 10
// baseline (1244.838 us; speedup 1.0000x reference)
//
#include <hip/hip_runtime.h>
#include <cstdint>

#define B 4096
#define D 256
#define H 512
#define K 10
#define NL 4
#define S 10
#define NOUT 30           // used head columns per d (3*K); tail C=64 unused
#define HEADW 94          // 3*K + C
#define ND (B*D)          // 1048576
#define NLOG 2560         // D*K   logits columns (exact fp32)
#define NMS  5120         // D*2K  means+scales columns (MFMA path)

typedef __bf16 bf16x8 __attribute__((ext_vector_type(8)));
typedef float  f32x16 __attribute__((ext_vector_type(16)));

// ---------------- threefry2x32 (JAX-exact) ----------------
__host__ __device__ inline void threefry2x32(uint32_t k0, uint32_t k1,
                                             uint32_t x0, uint32_t x1,
                                             uint32_t& o0, uint32_t& o1) {
  uint32_t ks2 = k0 ^ k1 ^ 0x1BD11BDAu;
#define TF_ROT(x, r) (((x) << (r)) | ((x) >> (32 - (r))))
#define TF_RND(r) { x0 += x1; x1 = TF_ROT(x1, r); x1 ^= x0; }
  x0 += k0; x1 += k1;
  TF_RND(13) TF_RND(15) TF_RND(26) TF_RND(6)
  x0 += k1; x1 += ks2 + 1u;
  TF_RND(17) TF_RND(29) TF_RND(16) TF_RND(24)
  x0 += ks2; x1 += k0 + 2u;
  TF_RND(13) TF_RND(15) TF_RND(26) TF_RND(6)
  x0 += k0; x1 += k1 + 3u;
  TF_RND(17) TF_RND(29) TF_RND(16) TF_RND(24)
  x0 += k1; x1 += ks2 + 4u;
  TF_RND(13) TF_RND(15) TF_RND(26) TF_RND(6)
  x0 += ks2; x1 += k0 + 5u;
  o0 = x0; o1 = x1;
#undef TF_RND
#undef TF_ROT
}

__device__ __forceinline__ uint32_t rb32(uint32_t k0, uint32_t k1, uint32_t idx) {
  uint32_t a, b;
  threefry2x32(k0, k1, 0u, idx, a, b);
  return a ^ b;
}

__device__ __forceinline__ float u01_from_bits(uint32_t bits) {
  return __uint_as_float((bits >> 9) | 0x3f800000u) - 1.0f;  // [0,1)
}

// XLA ErfInv32 (Giles single-precision polynomial)
__device__ __forceinline__ float erfinv_f32(float x) {
  float w = -log1pf(-x * x);
  float p;
  if (w < 5.0f) {
    w = w - 2.5f;
    p = 2.81022636e-08f;
    p = fmaf(p, w, 3.43273939e-07f);
    p = fmaf(p, w, -3.5233877e-06f);
    p = fmaf(p, w, -4.39150654e-06f);
    p = fmaf(p, w, 0.00021858087f);
    p = fmaf(p, w, -0.00125372503f);
    p = fmaf(p, w, -0.00417768164f);
    p = fmaf(p, w, 0.246640727f);
    p = fmaf(p, w, 1.50140941f);
  } else {
    w = sqrtf(w) - 3.0f;
    p = -0.000200214257f;
    p = fmaf(p, w, 0.000100950558f);
    p = fmaf(p, w, 0.00134934322f);
    p = fmaf(p, w, -0.00367342844f);
    p = fmaf(p, w, 0.00573950773f);
    p = fmaf(p, w, -0.0076224613f);
    p = fmaf(p, w, 0.00943887047f);
    p = fmaf(p, w, 1.00167406f);
    p = fmaf(p, w, 2.83297682f);
  }
  return p * x;
}

// ---------------- bf16 split helpers (R2-verified) ----------------
__device__ __forceinline__ unsigned short bf16_rne(float x) {
  uint32_t u = __float_as_uint(x);
  uint32_t r = u + 0x7fffu + ((u >> 16) & 1u);
  return (unsigned short)(r >> 16);
}

__device__ __forceinline__ void split2(float x, short& hi, short& lo) {
  unsigned short hb = bf16_rne(x);
  float hf = __uint_as_float((uint32_t)hb << 16);
  hi = (short)hb;
  lo = (short)bf16_rne(x - hf);
}

// ---------------- async global->LDS (16B/lane) ----------------
__device__ __forceinline__ void gload16(const void* g, void* l) {
  __builtin_amdgcn_global_load_lds(
      (const __attribute__((address_space(1))) void*)g,
      (__attribute__((address_space(3))) void*)l, 16, 0, 0);
}

// stage ROWS x 32 bf16 tile (row-major, 64B rows) from global [rows][512]
template <int ROWS>
__device__ __forceinline__ void stage_region(const short* __restrict__ g,
                                             short* l, int wid, int lane) {
#pragma unroll
  for (int c = wid; c < ROWS / 16; c += 4) {
    const short* gp = g + (size_t)(c * 16 + (lane >> 2)) * 512 + (lane & 3) * 8;
    gload16(gp, l + c * 512);
  }
}

// ---------------- prep: xcat = [x*mask, mask]  (bit-identical to R1) ------
__global__ __launch_bounds__(256) void prep_kernel(const float* __restrict__ x,
                                                   const float* __restrict__ mask,
                                                   float* __restrict__ xcat) {
  int i = blockIdx.x * 256 + threadIdx.x;  // over B*512
  if (i >= B * 2 * D) return;
  int b = i >> 9, c = i & 511;
  float v = (c < D) ? x[b * D + c] * mask[b * D + c] : mask[b * D + (c - D)];
  xcat[i] = v;
}

// ---------------- logit weight gather: wsgL[k][c] = Wf[k][(c/10)*94 + c%10]
__global__ __launch_bounds__(256) void wgatherL(const float* __restrict__ Wf,
                                                float* __restrict__ wsgL) {
  int c = blockIdx.x * 256 + threadIdx.x;  // 0..2559
  int k = blockIdx.y;                      // 0..511
  int dd = c / K, j = c - dd * K;
  wsgL[(size_t)k * NLOG + c] = Wf[(size_t)k * (D * HEADW) + dd * HEADW + j];
}

// ---- MS weight transpose + 2-split: Wf[512][24064] -> wms hi/lo [5120][512]
__global__ __launch_bounds__(256) void wsplit_ms(const float* __restrict__ Wf,
                                                 short* __restrict__ whi,
                                                 short* __restrict__ wlo) {
  __shared__ float tile[32][33];
  int n0 = blockIdx.x * 32, k0 = blockIdx.y * 32;
  int tx = threadIdx.x & 31, ty = threadIdx.x >> 5;  // 32 x 8
#pragma unroll
  for (int r = 0; r < 4; ++r) {
    int k = k0 + ty + r * 8;
    int n = n0 + tx;
    int dd = n / 20, j = n - dd * 20;
    tile[ty + r * 8][tx] = Wf[(size_t)k * (D * HEADW) + dd * HEADW + 10 + j];
  }
  __syncthreads();
#pragma unroll
  for (int r = 0; r < 4; ++r) {
    int n = n0 + ty + r * 8;
    int k = k0 + tx;
    float v = tile[tx][ty + r * 8];
    short hb, lb;
    split2(v, hb, lb);
    whi[(size_t)n * 512 + k] = hb;
    wlo[(size_t)n * 512 + k] = lb;
  }
}

// ---------------- fp32 trunk GEMM (bit-identical chains to R1/R4) --------
// C(4096x512) = [relu?](A) @ W(512x512) + bias [+ res]
// Round 10: 64x64 tile (R6 shape, 16 FMA per 2 LDS-reads per kk) but
// BK=32 DOUBLE-BUFFERED, one barrier per step (16 total, same as before)
// with every drain sitting AFTER a 32-kk compute phase:
//   barrier -> [stageW(kc+1) async + loadA(kc+1)->regs] -> compute(cur)
//   -> writeA regs->buf nxt (T14: vmcnt wait lands post-compute)
// LDS stays 33792 B (= R6 gemm_head), occupancy unchanged (grid-limited
// 2 blocks/CU).  Per-output fmaf chain ascending k, single chain ->
// h bit-identical to R1/R6.
template <int RELU, int RES>
__global__ __launch_bounds__(256) void gemm_trunk(const float* __restrict__ A,
                                                  const float* __restrict__ W,
                                                  const float* __restrict__ bias,
                                                  const float* res, float* C) {
  __shared__ __align__(16) float smem[8448];   // 33792 B
  // As[cur] = smem + cur*2176  ([32k][68m], pad like R6)
  // Ws[cur] = smem + 4352 + cur*2048  ([32k][64n])
  const int tid = threadIdx.x;
  const int lane = tid & 63, wid = tid >> 6;
  const int tx = tid & 15, ty = tid >> 4;
  const int bm = blockIdx.y * 64, bn = blockIdx.x * 64;
  const int ls = tid & 7, lm = tid >> 3;   // A-load: k-slot(8), row(32)

  float acc[4][4] = {};
  float4 fA[2];

  // ---- prologue: tile 0 into buf 0 ----
#pragma unroll
  for (int c = wid; c < 8; c += 4) {
    gload16(W + (size_t)(c * 4 + (lane >> 4)) * H + bn + (lane & 15) * 4,
            smem + 4352 + c * 256 + lane * 4);
  }
#pragma unroll
  for (int r = 0; r < 2; ++r) {
    fA[r] = *(const float4*)(A + (size_t)(bm + lm + 32 * r) * H + 4 * ls);
  }
#pragma unroll
  for (int r = 0; r < 2; ++r) {
    int m = lm + 32 * r;
    float4 f = fA[r];
    if (RELU) {
      f.x = fmaxf(f.x, 0.0f); f.y = fmaxf(f.y, 0.0f);
      f.z = fmaxf(f.z, 0.0f); f.w = fmaxf(f.w, 0.0f);
    }
    smem[(4 * ls + 0) * 68 + m] = f.x;
    smem[(4 * ls + 1) * 68 + m] = f.y;
    smem[(4 * ls + 2) * 68 + m] = f.z;
    smem[(4 * ls + 3) * 68 + m] = f.w;
  }

  int cur = 0;
  for (int kc = 0; kc < 16; ++kc) {
    __syncthreads();                       // buf cur ready
    const int nxt = cur ^ 1;
    if (kc < 15) {
      const int k0 = (kc + 1) * 32;
      // W: async global->LDS into buf nxt (flies under compute)
#pragma unroll
      for (int c = wid; c < 8; c += 4) {
        gload16(W + (size_t)(k0 + c * 4 + (lane >> 4)) * H + bn + (lane & 15) * 4,
                smem + 4352 + nxt * 2048 + c * 256 + lane * 4);
      }
      // A: issue global->reg loads now; LDS-write AFTER compute (T14)
#pragma unroll
      for (int r = 0; r < 2; ++r) {
        fA[r] = *(const float4*)(A + (size_t)(bm + lm + 32 * r) * H + k0 + 4 * ls);
      }
    }
    // ---- compute 32 kk on buf cur ----
    const float* As = smem + cur * 2176;
    const float* Ws = smem + 4352 + cur * 2048;
#pragma unroll
    for (int kk = 0; kk < 32; ++kk) {
      float4 a4 = *(const float4*)(As + kk * 68 + ty * 4);
      float4 b4 = *(const float4*)(Ws + kk * 64 + tx * 4);
      float a[4] = {a4.x, a4.y, a4.z, a4.w};
      float b[4] = {b4.x, b4.y, b4.z, b4.w};
#pragma unroll
      for (int i = 0; i < 4; ++i)
#pragma unroll
        for (int j = 0; j < 4; ++j) acc[i][j] = fmaf(a[i], b[j], acc[i][j]);
    }
    // ---- write prefetched A into buf nxt (vmcnt wait lands here) ----
    if (kc < 15) {
      float* Asn = smem + nxt * 2176;
#pragma unroll
      for (int r = 0; r < 2; ++r) {
        int m = lm + 32 * r;
        float4 f = fA[r];
        if (RELU) {
          f.x = fmaxf(f.x, 0.0f); f.y = fmaxf(f.y, 0.0f);
          f.z = fmaxf(f.z, 0.0f); f.w = fmaxf(f.w, 0.0f);
        }
        Asn[(4 * ls + 0) * 68 + m] = f.x;
        Asn[(4 * ls + 1) * 68 + m] = f.y;
        Asn[(4 * ls + 2) * 68 + m] = f.z;
        Asn[(4 * ls + 3) * 68 + m] = f.w;
      }
    }
    cur ^= 1;
  }
#pragma unroll
  for (int i = 0; i < 4; ++i) {
    int row = bm + ty * 4 + i;
#pragma unroll
    for (int j = 0; j < 4; ++j) {
      int col = bn + tx * 4 + j;
      float v = acc[i][j] + bias[col];
      if (RES) v = res[(size_t)row * H + col] + v;  // same order as R1
      C[(size_t)row * H + col] = v;
    }
  }
}

// ---------------- FUSED head GEMM: logits (fp32, exact) + ms (MFMA) ------
// EXACT R6-measured code (350 us): default block mapping (no swizzle),
// split headL/headMS outputs, tx*8 Ws reads, float4 logits stores.
__global__ __launch_bounds__(256) void gemm_head(const float* __restrict__ A,
                                                 const float* __restrict__ Wg,
                                                 const short* __restrict__ Bh,
                                                 const short* __restrict__ Bl,
                                                 const float* __restrict__ bf,
                                                 float* __restrict__ headL,
                                                 float* __restrict__ headMS) {
  __shared__ __align__(16) float smem[8448];  // 33792 B shared by both paths
  const int tid = threadIdx.x;
  const int lane = tid & 63, wid = tid >> 6;
  const int bm = blockIdx.y * 128;

  if (blockIdx.x < 20) {
    // ---------- logits path (exact fp32; frozen fmaf chains) ----------
    float* As = smem;          // 32*136
    float* Ws = smem + 4352;   // 32*128
    const int tx = tid & 15, ty = tid >> 4;
    const int bn = blockIdx.x * 128;
    const int ls = tid & 7, lm = tid >> 3;

    float acc[8][8] = {};

    for (int k0 = 0; k0 < H; k0 += 32) {
#pragma unroll
      for (int c = wid; c < 16; c += 4) {
        gload16(Wg + (size_t)(k0 + c * 2 + (lane >> 5)) * NLOG + bn + (lane & 31) * 4,
                Ws + c * 256 + lane * 4);
      }
#pragma unroll
      for (int r = 0; r < 4; ++r) {
        int m = lm + 32 * r;
        float4 f = *(const float4*)(A + (size_t)(bm + m) * H + k0 + 4 * ls);
        As[(4 * ls + 0) * 136 + m] = f.x;
        As[(4 * ls + 1) * 136 + m] = f.y;
        As[(4 * ls + 2) * 136 + m] = f.z;
        As[(4 * ls + 3) * 136 + m] = f.w;
      }
      __syncthreads();
#pragma unroll
      for (int kk = 0; kk < 32; ++kk) {
        float a[8], b[8];
        *(float4*)(a + 0) = *(const float4*)(As + kk * 136 + ty * 8);
        *(float4*)(a + 4) = *(const float4*)(As + kk * 136 + ty * 8 + 4);
        *(float4*)(b + 0) = *(const float4*)(Ws + kk * 128 + tx * 8);
        *(float4*)(b + 4) = *(const float4*)(Ws + kk * 128 + tx * 8 + 4);
#pragma unroll
        for (int i = 0; i < 8; ++i)
#pragma unroll
          for (int j = 0; j < 8; ++j) acc[i][j] = fmaf(a[i], b[j], acc[i][j]);
      }
      __syncthreads();
    }
    // epilogue: same values (acc + bias), vectorized contiguous stores
    float bias[8];
#pragma unroll
    for (int j = 0; j < 8; ++j) {
      int c = bn + tx * 8 + j;
      int dd = c / K, jj = c - dd * K;
      bias[j] = bf[dd * HEADW + jj];
    }
#pragma unroll
    for (int i = 0; i < 8; ++i) {
      int row = bm + ty * 8 + i;
      float4 v0, v1;
      v0.x = acc[i][0] + bias[0]; v0.y = acc[i][1] + bias[1];
      v0.z = acc[i][2] + bias[2]; v0.w = acc[i][3] + bias[3];
      v1.x = acc[i][4] + bias[4]; v1.y = acc[i][5] + bias[5];
      v1.z = acc[i][6] + bias[6]; v1.w = acc[i][7] + bias[7];
      float* dst = headL + (size_t)row * NLOG + bn + tx * 8;
      *(float4*)dst = v0;
      *(float4*)(dst + 4) = v1;
    }
  } else {
    // ---------- ms path (MFMA; R0-verified structure, frozen) ----------
    short* lds = (short*)smem;   // uses 16384 B
    const int wm = wid >> 1, wn = wid & 1;
    const int bn = (blockIdx.x - 20) * 128;
    const int ls = tid & 7, lm = tid >> 3;

    short* ldsAh = lds;
    short* ldsAl = lds + 4096;
    short* ldsBh = lds + 8192;
    short* ldsBl = lds + 12288;

    const short* gBh = Bh + (size_t)bn * 512;
    const short* gBl = Bl + (size_t)bn * 512;

    f32x16 acc[2][2];
#pragma unroll
    for (int mt = 0; mt < 2; ++mt)
#pragma unroll
      for (int nt = 0; nt < 2; ++nt)
#pragma unroll
        for (int i = 0; i < 16; ++i) acc[mt][nt][i] = 0.0f;

    for (int k0 = 0; k0 < 512; k0 += 32) {
      stage_region<128>(gBh + k0, ldsBh, wid, lane);
      stage_region<128>(gBl + k0, ldsBl, wid, lane);
#pragma unroll
      for (int r = 0; r < 4; ++r) {
        int m = lm + 32 * r;
        float4 f = *(const float4*)(A + (size_t)(bm + m) * H + k0 + 4 * ls);
        short4 h4, l4;
        split2(f.x, h4.x, l4.x); split2(f.y, h4.y, l4.y);
        split2(f.z, h4.z, l4.z); split2(f.w, h4.w, l4.w);
        *(short4*)(ldsAh + m * 32 + 4 * ls) = h4;
        *(short4*)(ldsAl + m * 32 + 4 * ls) = l4;
      }
      __syncthreads();
#pragma unroll
      for (int sub = 0; sub < 2; ++sub) {
        bf16x8 ah[2], al[2], bh[2], bl[2];
#pragma unroll
        for (int mt = 0; mt < 2; ++mt) {
          int r = wm * 64 + mt * 32 + (lane & 31);
          int off = r * 32 + sub * 16 + (lane >> 5) * 8;
          ah[mt] = *(const bf16x8*)(ldsAh + off);
          al[mt] = *(const bf16x8*)(ldsAl + off);
        }
#pragma unroll
        for (int nt = 0; nt < 2; ++nt) {
          int r = wn * 64 + nt * 32 + (lane & 31);
          int off = r * 32 + sub * 16 + (lane >> 5) * 8;
          bh[nt] = *(const bf16x8*)(ldsBh + off);
          bl[nt] = *(const bf16x8*)(ldsBl + off);
        }
#pragma unroll
        for (int mt = 0; mt < 2; ++mt)
#pragma unroll
          for (int nt = 0; nt < 2; ++nt) {
            acc[mt][nt] = __builtin_amdgcn_mfma_f32_32x32x16_bf16(ah[mt], bh[nt], acc[mt][nt], 0, 0, 0);
            acc[mt][nt] = __builtin_amdgcn_mfma_f32_32x32x16_bf16(ah[mt], bl[nt], acc[mt][nt], 0, 0, 0);
            acc[mt][nt] = __builtin_amdgcn_mfma_f32_32x32x16_bf16(al[mt], bh[nt], acc[mt][nt], 0, 0, 0);
          }
      }
      __syncthreads();
    }

#pragma unroll
    for (int mt = 0; mt < 2; ++mt)
#pragma unroll
      for (int nt = 0; nt < 2; ++nt) {
        int col = bn + wn * 64 + nt * 32 + (lane & 31);   // 0..5119
        int rbase = bm + wm * 64 + mt * 32 + 4 * (lane >> 5);
        int dd = col / 20, j = col - dd * 20;
#pragma unroll
        for (int reg = 0; reg < 16; ++reg) {
          int row = rbase + (reg & 3) + 8 * (reg >> 2);
          float v = acc[mt][nt][reg] + bf[dd * HEADW + 10 + j];
          if (j >= 10) v = (fmaxf(v, 0.0f) + log1pf(expf(-fabsf(v)))) + 0.001f;
          headMS[(size_t)row * NMS + col] = v;   // contiguous cols, no RMW mix
        }
      }
  }
}

// ---------------- tail compaction -----------------------------------------
__global__ __launch_bounds__(256) void init_counter(int* counter) {
  if (threadIdx.x == 0 && blockIdx.x == 0) *counter = 0;
}

__global__ __launch_bounds__(256) void compact_zero(const float* __restrict__ mask,
                                                    float* __restrict__ out_ll,
                                                    float* __restrict__ out_s,
                                                    float* __restrict__ out_mean,
                                                    int* __restrict__ list,
                                                    int* __restrict__ counter) {
  int idx = blockIdx.x * 256 + threadIdx.x;
  if (idx >= ND) return;
  if (mask[idx] != 0.0f) {   // observed -> q = 0 -> outputs all zero
    int b = idx >> 8, d = idx & (D - 1);
    out_ll[idx] = 0.0f;
    out_mean[idx] = 0.0f;
#pragma unroll
    for (int s = 0; s < S; ++s) out_s[((size_t)b * S + s) * D + d] = 0.0f;
  } else {
    int pos = atomicAdd(counter, 1);   // compiler aggregates per-wave (G12)
    list[pos] = idx;
  }
}

// ---------------- fused tail on compacted list (frozen R6/R7 numerics) ---
__global__ __launch_bounds__(256) void fused_tail(const float* __restrict__ headL,
                                                  const float* __restrict__ headMS,
                                                  const float* __restrict__ x,
                                                  const float* __restrict__ mask,
                                                  const int* __restrict__ list,
                                                  const int* __restrict__ counter,
                                                  float* __restrict__ out_ll,
                                                  float* __restrict__ out_s,
                                                  float* __restrict__ out_mean,
                                                  uint32_t kc0, uint32_t kc1,
                                                  uint32_t kn0, uint32_t kn1) {
  int i = blockIdx.x * 256 + threadIdx.x;
  if (i >= *counter) return;
  int idx = list[i];
  int b = idx >> 8, d = idx & (D - 1);
  const float* hpL = headL + (size_t)idx * K;        // row*2560 + d*10
  const float* hpM = headMS + (size_t)idx * (2 * K); // row*5120 + d*20
  float lg[K], mn[K], sc[K];
#pragma unroll
  for (int k = 0; k < K; ++k) { lg[k] = hpL[k]; mn[k] = hpM[k]; sc[k] = hpM[K + k]; }
  float q = 1.0f - mask[idx];          // == 1.0 exactly on this list
  float xu = x[idx] * q;
  float m = lg[0];
#pragma unroll
  for (int k = 1; k < K; ++k) m = fmaxf(m, lg[k]);
  float e[K];
  float sum = 0.0f;
#pragma unroll
  for (int k = 0; k < K; ++k) { e[k] = expf(lg[k] - m); sum += e[k]; }
  float lse = logf(sum);
  float a[K];
  float amax = -3.402823466e38f;
#pragma unroll
  for (int k = 0; k < K; ++k) {
    float z = (xu - mn[k]) / sc[k];
    float cll = -0.5f * z * z - logf(sc[k]) - 0.9189385332046727f;
    float lw = (lg[k] - m) - lse;
    a[k] = lw + cll;
    amax = fmaxf(amax, a[k]);
  }
  float s2 = 0.0f;
#pragma unroll
  for (int k = 0; k < K; ++k) s2 += expf(a[k] - amax);
  out_ll[idx] = (logf(s2) + amax) * q;
  float pm = 0.0f;
#pragma unroll
  for (int k = 0; k < K; ++k) pm += (e[k] / sum) * mn[k];
  out_mean[idx] = pm * q;
  float inv_e[K];
#pragma unroll
  for (int k = 0; k < K; ++k) inv_e[k] = 1.0f / e[k];
  for (int s = 0; s < S; ++s) {
    uint32_t t32 = (uint32_t)s * (uint32_t)ND + (uint32_t)idx;
    uint32_t base = t32 * (uint32_t)K;
    int best = 0;
    float rbest = 3.402823466e38f;
#pragma unroll
    for (int k = 0; k < K; ++k) {
      uint32_t bits = rb32(kc0, kc1, base + (uint32_t)k);
      float u = u01_from_bits(bits);
      float wv = -__log2f(u);              // hw v_log_f32; u=0 -> +inf (never wins)
      float r = wv * inv_e[k];
      if (r < rbest) { rbest = r; best = k; }  // first-min == reference first-max
    }
    uint32_t ebits = rb32(kn0, kn1, t32);
    float f = u01_from_bits(ebits);
    float r2 = f * 2.0f + (-0.99999994f);
    r2 = fmaxf(r2, -0.99999994f);
    float eps = 1.4142135623730951f * erfinv_f32(r2);
    out_s[((size_t)b * S + s) * D + d] = (mn[best] + sc[best] * eps) * q;
  }
}

// ---------------- launch ----------------
extern "C" void kernel_launch(void* const* d_in, const int* in_sizes, int n_in,
                              void* d_out, int out_size, void* d_ws, size_t ws_size,
                              hipStream_t stream) {
  const float* x    = (const float*)d_in[0];
  const float* mask = (const float*)d_in[1];
  const float* W_in = (const float*)d_in[2];
  const float* b_in = (const float*)d_in[3];
  const float* W1   = (const float*)d_in[4];
  const float* b1   = (const float*)d_in[5];
  const float* W2   = (const float*)d_in[6];
  const float* b2   = (const float*)d_in[7];
  const float* Wf   = (const float*)d_in[8];
  const float* bf   = (const float*)d_in[9];

  // workspace (unchanged footprint 149,946,372 B):
  //   [0, 41943040)            headL  B*2560 f32   (xcat/t alias: dead early)
  //   [41943040, 125829120)    headMS B*5120 f32
  //   [125829120, 134217728)   h      B*512  f32
  //   [134217728, 139460608)   wsgL / list alias
  //   [139460608, 149946368)   wms_h, wms_l
  //   [149946368, ...)         counter
  char* w = (char*)d_ws;
  float* headL  = (float*)w;                     // B*2560 f32
  float* headMS = (float*)(w + 41943040);        // B*5120 f32
  float* xcat   = headL;                         // alias: dead after gemm0
  float* t      = headL;                         // alias: dead before fin
  float* h      = (float*)(w + 125829120);       // B*512 f32 (live through fin)
  float* wsgL   = (float*)(w + 134217728);       // 512*2560 f32 logit weights
  int*   list   = (int*)(w + 134217728);         // alias wsgL: ND ints (4 MB)
  short* wms_h  = (short*)(w + 139460608);       // 5120*512 bf16
  short* wms_l  = (short*)(w + 144703488);       // 5120*512 bf16
  int*   counter = (int*)(w + 149946368);        // 4 B

  float* out_ll   = (float*)d_out;               // (B,D)
  float* out_s    = out_ll + (size_t)ND;         // (B,S,D)
  float* out_mean = out_s + (size_t)ND * S;      // (B,D)

  wgatherL<<<dim3(NLOG / 256, 512), 256, 0, stream>>>(Wf, wsgL);
  wsplit_ms<<<dim3(NMS / 32, 512 / 32), 256, 0, stream>>>(Wf, wms_h, wms_l);

  prep_kernel<<<(B * 2 * D) / 256, 256, 0, stream>>>(x, mask, xcat);

  dim3 gtr(H / 64, B / 64);  // (8, 64) = 512 blocks, 2 per CU, 8 waves/CU
  gemm_trunk<0, 0><<<gtr, 256, 0, stream>>>(xcat, W_in, b_in, nullptr, h);
  for (int l = 0; l < NL; ++l) {
    gemm_trunk<1, 0><<<gtr, 256, 0, stream>>>(h, W1 + (size_t)l * H * H,
                                              b1 + (size_t)l * H, nullptr, t);
    gemm_trunk<1, 1><<<gtr, 256, 0, stream>>>(t, W2 + (size_t)l * H * H,
                                              b2 + (size_t)l * H, h, h);
  }

  // fused logits (fp32, x<20) + ms (MFMA, x>=20): 60x32 = 1920 blocks
  gemm_head<<<dim3(60, B / 128), 256, 0, stream>>>(h, wsgL, wms_h, wms_l, bf,
                                                   headL, headMS);

  // compaction (after gemm_head: list overwrites wsgL)
  init_counter<<<1, 256, 0, stream>>>(counter);
  compact_zero<<<ND / 256, 256, 0, stream>>>(mask, out_ll, out_s, out_mean,
                                             list, counter);

  uint32_t kc0, kc1, kn0, kn1;
  threefry2x32(0u, 1234u, 0u, 0u, kc0, kc1);
  threefry2x32(0u, 1234u, 0u, 1u, kn0, kn1);
  fused_tail<<<ND / 256, 256, 0, stream>>>(headL, headMS, x, mask, list, counter,
                                           out_ll, out_s, out_mean,
                                           kc0, kc1, kn0, kn1);
}

// Round 11
// 1139.783 us; speedup vs baseline: 1.0922x; 1.0922x over previous
//
#include <hip/hip_runtime.h>
#include <cstdint>

#define B 4096
#define D 256
#define H 512
#define K 10
#define NL 4
#define S 10
#define NOUT 30           // used head columns per d (3*K); tail C=64 unused
#define HEADW 94          // 3*K + C
#define ND (B*D)          // 1048576
#define NLOG 2560         // D*K   logits columns (exact fp32)
#define NMS  5120         // D*2K  means+scales columns (MFMA path)

typedef __bf16 bf16x8 __attribute__((ext_vector_type(8)));
typedef float  f32x16 __attribute__((ext_vector_type(16)));

// ---------------- threefry2x32 (JAX-exact) ----------------
__host__ __device__ inline void threefry2x32(uint32_t k0, uint32_t k1,
                                             uint32_t x0, uint32_t x1,
                                             uint32_t& o0, uint32_t& o1) {
  uint32_t ks2 = k0 ^ k1 ^ 0x1BD11BDAu;
#define TF_ROT(x, r) (((x) << (r)) | ((x) >> (32 - (r))))
#define TF_RND(r) { x0 += x1; x1 = TF_ROT(x1, r); x1 ^= x0; }
  x0 += k0; x1 += k1;
  TF_RND(13) TF_RND(15) TF_RND(26) TF_RND(6)
  x0 += k1; x1 += ks2 + 1u;
  TF_RND(17) TF_RND(29) TF_RND(16) TF_RND(24)
  x0 += ks2; x1 += k0 + 2u;
  TF_RND(13) TF_RND(15) TF_RND(26) TF_RND(6)
  x0 += k0; x1 += k1 + 3u;
  TF_RND(17) TF_RND(29) TF_RND(16) TF_RND(24)
  x0 += k1; x1 += ks2 + 4u;
  TF_RND(13) TF_RND(15) TF_RND(26) TF_RND(6)
  x0 += ks2; x1 += k0 + 5u;
  o0 = x0; o1 = x1;
#undef TF_RND
#undef TF_ROT
}

__device__ __forceinline__ uint32_t rb32(uint32_t k0, uint32_t k1, uint32_t idx) {
  uint32_t a, b;
  threefry2x32(k0, k1, 0u, idx, a, b);
  return a ^ b;
}

__device__ __forceinline__ float u01_from_bits(uint32_t bits) {
  return __uint_as_float((bits >> 9) | 0x3f800000u) - 1.0f;  // [0,1)
}

// XLA ErfInv32 (Giles single-precision polynomial)
__device__ __forceinline__ float erfinv_f32(float x) {
  float w = -log1pf(-x * x);
  float p;
  if (w < 5.0f) {
    w = w - 2.5f;
    p = 2.81022636e-08f;
    p = fmaf(p, w, 3.43273939e-07f);
    p = fmaf(p, w, -3.5233877e-06f);
    p = fmaf(p, w, -4.39150654e-06f);
    p = fmaf(p, w, 0.00021858087f);
    p = fmaf(p, w, -0.00125372503f);
    p = fmaf(p, w, -0.00417768164f);
    p = fmaf(p, w, 0.246640727f);
    p = fmaf(p, w, 1.50140941f);
  } else {
    w = sqrtf(w) - 3.0f;
    p = -0.000200214257f;
    p = fmaf(p, w, 0.000100950558f);
    p = fmaf(p, w, 0.00134934322f);
    p = fmaf(p, w, -0.00367342844f);
    p = fmaf(p, w, 0.00573950773f);
    p = fmaf(p, w, -0.0076224613f);
    p = fmaf(p, w, 0.00943887047f);
    p = fmaf(p, w, 1.00167406f);
    p = fmaf(p, w, 2.83297682f);
  }
  return p * x;
}

// ---------------- bf16 split helpers (R2-verified) ----------------
__device__ __forceinline__ unsigned short bf16_rne(float x) {
  uint32_t u = __float_as_uint(x);
  uint32_t r = u + 0x7fffu + ((u >> 16) & 1u);
  return (unsigned short)(r >> 16);
}

__device__ __forceinline__ void split2(float x, short& hi, short& lo) {
  unsigned short hb = bf16_rne(x);
  float hf = __uint_as_float((uint32_t)hb << 16);
  hi = (short)hb;
  lo = (short)bf16_rne(x - hf);
}

// ---------------- async global->LDS (16B/lane) ----------------
__device__ __forceinline__ void gload16(const void* g, void* l) {
  __builtin_amdgcn_global_load_lds(
      (const __attribute__((address_space(1))) void*)g,
      (__attribute__((address_space(3))) void*)l, 16, 0, 0);
}

// stage ROWS x 32 bf16 tile (row-major, 64B rows) from global [rows][512]
template <int ROWS>
__device__ __forceinline__ void stage_region(const short* __restrict__ g,
                                             short* l, int wid, int lane) {
#pragma unroll
  for (int c = wid; c < ROWS / 16; c += 4) {
    const short* gp = g + (size_t)(c * 16 + (lane >> 2)) * 512 + (lane & 3) * 8;
    gload16(gp, l + c * 512);
  }
}

// ---------------- logit weight gather: wsgL[k][c] = Wf[k][(c/10)*94 + c%10]
__global__ __launch_bounds__(256) void wgatherL(const float* __restrict__ Wf,
                                                float* __restrict__ wsgL) {
  int c = blockIdx.x * 256 + threadIdx.x;  // 0..2559
  int k = blockIdx.y;                      // 0..511
  int dd = c / K, j = c - dd * K;
  wsgL[(size_t)k * NLOG + c] = Wf[(size_t)k * (D * HEADW) + dd * HEADW + j];
}

// ---- MS weight transpose + 2-split: Wf[512][24064] -> wms hi/lo [5120][512]
__global__ __launch_bounds__(256) void wsplit_ms(const float* __restrict__ Wf,
                                                 short* __restrict__ whi,
                                                 short* __restrict__ wlo) {
  __shared__ float tile[32][33];
  int n0 = blockIdx.x * 32, k0 = blockIdx.y * 32;
  int tx = threadIdx.x & 31, ty = threadIdx.x >> 5;  // 32 x 8
#pragma unroll
  for (int r = 0; r < 4; ++r) {
    int k = k0 + ty + r * 8;
    int n = n0 + tx;
    int dd = n / 20, j = n - dd * 20;
    tile[ty + r * 8][tx] = Wf[(size_t)k * (D * HEADW) + dd * HEADW + 10 + j];
  }
  __syncthreads();
#pragma unroll
  for (int r = 0; r < 4; ++r) {
    int n = n0 + ty + r * 8;
    int k = k0 + tx;
    float v = tile[tx][ty + r * 8];
    short hb, lb;
    split2(v, hb, lb);
    whi[(size_t)n * 512 + k] = hb;
    wlo[(size_t)n * 512 + k] = lb;
  }
}

// ---------------- fp32 trunk GEMM (bit-identical chains to R1/R4) --------
// C(4096x512) = [relu?](A) @ W(512x512) + bias [+ res]
// 64x64 tile, BK=64, 2 barriers/step — the R6-measured config (best of 4
// structural variants tried; 32x64, BK=32-dbuf, +swizzle all regressed).
// FP: fuse prep into the A-load of trunk0 — reads x,mask directly and
// computes x*mask inline (same fp op => h bit-identical; the c<D branch
// is wave-uniform because 64-wide k-steps never straddle c=256).
template <int RELU, int RES, int FP>
__global__ __launch_bounds__(256) void gemm_trunk(const float* __restrict__ A,
                                                  const float* __restrict__ W,
                                                  const float* __restrict__ bias,
                                                  const float* res, float* C,
                                                  const float* __restrict__ xp,
                                                  const float* __restrict__ mp) {
  __shared__ float As[64 * 68];  // [k][m], stride 68 (272B, 16B-aligned)
  __shared__ float Ws[64 * 64];  // [k][n], stride 64
  const int tid = threadIdx.x;
  const int lane = tid & 63, wid = tid >> 6;
  const int tx = tid & 15, ty = tid >> 4;
  const int bm = blockIdx.y * 64, bn = blockIdx.x * 64;
  const int ls = tid & 15, lm = tid >> 4;  // A-load: k-slot(16), row(16)

  float acc[4][4] = {};

  for (int k0 = 0; k0 < H; k0 += 64) {
#pragma unroll
    for (int c = wid; c < 16; c += 4) {
      gload16(W + (size_t)(k0 + c * 4 + (lane >> 4)) * H + bn + (lane & 15) * 4,
              Ws + c * 256 + lane * 4);
    }
#pragma unroll
    for (int r = 0; r < 4; ++r) {
      int m = lm + 16 * r;
      float4 f;
      if (FP) {
        int c = k0 + 4 * ls;               // 4-aligned; never straddles D
        const int brow = bm + m;
        if (c < D) {
          float4 xv = *(const float4*)(xp + (size_t)brow * D + c);
          float4 mv = *(const float4*)(mp + (size_t)brow * D + c);
          f.x = xv.x * mv.x; f.y = xv.y * mv.y;
          f.z = xv.z * mv.z; f.w = xv.w * mv.w;
        } else {
          f = *(const float4*)(mp + (size_t)brow * D + (c - D));
        }
      } else {
        f = *(const float4*)(A + (size_t)(bm + m) * H + k0 + 4 * ls);
      }
      if (RELU) {
        f.x = fmaxf(f.x, 0.0f); f.y = fmaxf(f.y, 0.0f);
        f.z = fmaxf(f.z, 0.0f); f.w = fmaxf(f.w, 0.0f);
      }
      As[(4 * ls + 0) * 68 + m] = f.x;
      As[(4 * ls + 1) * 68 + m] = f.y;
      As[(4 * ls + 2) * 68 + m] = f.z;
      As[(4 * ls + 3) * 68 + m] = f.w;
    }
    __syncthreads();
#pragma unroll
    for (int kk = 0; kk < 64; ++kk) {
      float4 a4 = *(const float4*)(As + kk * 68 + ty * 4);
      float4 b4 = *(const float4*)(Ws + kk * 64 + tx * 4);
      float a[4] = {a4.x, a4.y, a4.z, a4.w};
      float b[4] = {b4.x, b4.y, b4.z, b4.w};
#pragma unroll
      for (int i = 0; i < 4; ++i)
#pragma unroll
        for (int j = 0; j < 4; ++j) acc[i][j] = fmaf(a[i], b[j], acc[i][j]);
    }
    __syncthreads();
  }
#pragma unroll
  for (int i = 0; i < 4; ++i) {
    int row = bm + ty * 4 + i;
#pragma unroll
    for (int j = 0; j < 4; ++j) {
      int col = bn + tx * 4 + j;
      float v = acc[i][j] + bias[col];
      if (RES) v = res[(size_t)row * H + col] + v;  // same order as R1
      C[(size_t)row * H + col] = v;
    }
  }
}

// ---------------- FUSED head GEMM: logits (fp32, exact) + ms (MFMA) ------
// EXACT R6-measured code (350 us, reproduced twice): default block
// mapping (no swizzle), split headL/headMS outputs, tx*8 Ws reads,
// float4 logits stores.
__global__ __launch_bounds__(256) void gemm_head(const float* __restrict__ A,
                                                 const float* __restrict__ Wg,
                                                 const short* __restrict__ Bh,
                                                 const short* __restrict__ Bl,
                                                 const float* __restrict__ bf,
                                                 float* __restrict__ headL,
                                                 float* __restrict__ headMS) {
  __shared__ __align__(16) float smem[8448];  // 33792 B shared by both paths
  const int tid = threadIdx.x;
  const int lane = tid & 63, wid = tid >> 6;
  const int bm = blockIdx.y * 128;

  if (blockIdx.x < 20) {
    // ---------- logits path (exact fp32; frozen fmaf chains) ----------
    float* As = smem;          // 32*136
    float* Ws = smem + 4352;   // 32*128
    const int tx = tid & 15, ty = tid >> 4;
    const int bn = blockIdx.x * 128;
    const int ls = tid & 7, lm = tid >> 3;

    float acc[8][8] = {};

    for (int k0 = 0; k0 < H; k0 += 32) {
#pragma unroll
      for (int c = wid; c < 16; c += 4) {
        gload16(Wg + (size_t)(k0 + c * 2 + (lane >> 5)) * NLOG + bn + (lane & 31) * 4,
                Ws + c * 256 + lane * 4);
      }
#pragma unroll
      for (int r = 0; r < 4; ++r) {
        int m = lm + 32 * r;
        float4 f = *(const float4*)(A + (size_t)(bm + m) * H + k0 + 4 * ls);
        As[(4 * ls + 0) * 136 + m] = f.x;
        As[(4 * ls + 1) * 136 + m] = f.y;
        As[(4 * ls + 2) * 136 + m] = f.z;
        As[(4 * ls + 3) * 136 + m] = f.w;
      }
      __syncthreads();
#pragma unroll
      for (int kk = 0; kk < 32; ++kk) {
        float a[8], b[8];
        *(float4*)(a + 0) = *(const float4*)(As + kk * 136 + ty * 8);
        *(float4*)(a + 4) = *(const float4*)(As + kk * 136 + ty * 8 + 4);
        *(float4*)(b + 0) = *(const float4*)(Ws + kk * 128 + tx * 8);
        *(float4*)(b + 4) = *(const float4*)(Ws + kk * 128 + tx * 8 + 4);
#pragma unroll
        for (int i = 0; i < 8; ++i)
#pragma unroll
          for (int j = 0; j < 8; ++j) acc[i][j] = fmaf(a[i], b[j], acc[i][j]);
      }
      __syncthreads();
    }
    // epilogue: same values (acc + bias), vectorized contiguous stores
    float bias[8];
#pragma unroll
    for (int j = 0; j < 8; ++j) {
      int c = bn + tx * 8 + j;
      int dd = c / K, jj = c - dd * K;
      bias[j] = bf[dd * HEADW + jj];
    }
#pragma unroll
    for (int i = 0; i < 8; ++i) {
      int row = bm + ty * 8 + i;
      float4 v0, v1;
      v0.x = acc[i][0] + bias[0]; v0.y = acc[i][1] + bias[1];
      v0.z = acc[i][2] + bias[2]; v0.w = acc[i][3] + bias[3];
      v1.x = acc[i][4] + bias[4]; v1.y = acc[i][5] + bias[5];
      v1.z = acc[i][6] + bias[6]; v1.w = acc[i][7] + bias[7];
      float* dst = headL + (size_t)row * NLOG + bn + tx * 8;
      *(float4*)dst = v0;
      *(float4*)(dst + 4) = v1;
    }
  } else {
    // ---------- ms path (MFMA; R0-verified structure, frozen) ----------
    short* lds = (short*)smem;   // uses 16384 B
    const int wm = wid >> 1, wn = wid & 1;
    const int bn = (blockIdx.x - 20) * 128;
    const int ls = tid & 7, lm = tid >> 3;

    short* ldsAh = lds;
    short* ldsAl = lds + 4096;
    short* ldsBh = lds + 8192;
    short* ldsBl = lds + 12288;

    const short* gBh = Bh + (size_t)bn * 512;
    const short* gBl = Bl + (size_t)bn * 512;

    f32x16 acc[2][2];
#pragma unroll
    for (int mt = 0; mt < 2; ++mt)
#pragma unroll
      for (int nt = 0; nt < 2; ++nt)
#pragma unroll
        for (int i = 0; i < 16; ++i) acc[mt][nt][i] = 0.0f;

    for (int k0 = 0; k0 < 512; k0 += 32) {
      stage_region<128>(gBh + k0, ldsBh, wid, lane);
      stage_region<128>(gBl + k0, ldsBl, wid, lane);
#pragma unroll
      for (int r = 0; r < 4; ++r) {
        int m = lm + 32 * r;
        float4 f = *(const float4*)(A + (size_t)(bm + m) * H + k0 + 4 * ls);
        short4 h4, l4;
        split2(f.x, h4.x, l4.x); split2(f.y, h4.y, l4.y);
        split2(f.z, h4.z, l4.z); split2(f.w, h4.w, l4.w);
        *(short4*)(ldsAh + m * 32 + 4 * ls) = h4;
        *(short4*)(ldsAl + m * 32 + 4 * ls) = l4;
      }
      __syncthreads();
#pragma unroll
      for (int sub = 0; sub < 2; ++sub) {
        bf16x8 ah[2], al[2], bh[2], bl[2];
#pragma unroll
        for (int mt = 0; mt < 2; ++mt) {
          int r = wm * 64 + mt * 32 + (lane & 31);
          int off = r * 32 + sub * 16 + (lane >> 5) * 8;
          ah[mt] = *(const bf16x8*)(ldsAh + off);
          al[mt] = *(const bf16x8*)(ldsAl + off);
        }
#pragma unroll
        for (int nt = 0; nt < 2; ++nt) {
          int r = wn * 64 + nt * 32 + (lane & 31);
          int off = r * 32 + sub * 16 + (lane >> 5) * 8;
          bh[nt] = *(const bf16x8*)(ldsBh + off);
          bl[nt] = *(const bf16x8*)(ldsBl + off);
        }
#pragma unroll
        for (int mt = 0; mt < 2; ++mt)
#pragma unroll
          for (int nt = 0; nt < 2; ++nt) {
            acc[mt][nt] = __builtin_amdgcn_mfma_f32_32x32x16_bf16(ah[mt], bh[nt], acc[mt][nt], 0, 0, 0);
            acc[mt][nt] = __builtin_amdgcn_mfma_f32_32x32x16_bf16(ah[mt], bl[nt], acc[mt][nt], 0, 0, 0);
            acc[mt][nt] = __builtin_amdgcn_mfma_f32_32x32x16_bf16(al[mt], bh[nt], acc[mt][nt], 0, 0, 0);
          }
      }
      __syncthreads();
    }

#pragma unroll
    for (int mt = 0; mt < 2; ++mt)
#pragma unroll
      for (int nt = 0; nt < 2; ++nt) {
        int col = bn + wn * 64 + nt * 32 + (lane & 31);   // 0..5119
        int rbase = bm + wm * 64 + mt * 32 + 4 * (lane >> 5);
        int dd = col / 20, j = col - dd * 20;
#pragma unroll
        for (int reg = 0; reg < 16; ++reg) {
          int row = rbase + (reg & 3) + 8 * (reg >> 2);
          float v = acc[mt][nt][reg] + bf[dd * HEADW + 10 + j];
          if (j >= 10) v = (fmaxf(v, 0.0f) + log1pf(expf(-fabsf(v)))) + 0.001f;
          headMS[(size_t)row * NMS + col] = v;   // contiguous cols, no RMW mix
        }
      }
  }
}

// ---------------- tail compaction -----------------------------------------
__global__ __launch_bounds__(256) void compact_zero(const float* __restrict__ mask,
                                                    float* __restrict__ out_ll,
                                                    float* __restrict__ out_s,
                                                    float* __restrict__ out_mean,
                                                    int* __restrict__ list,
                                                    int* __restrict__ counter) {
  int idx = blockIdx.x * 256 + threadIdx.x;
  if (idx >= ND) return;
  if (mask[idx] != 0.0f) {   // observed -> q = 0 -> outputs all zero
    int b = idx >> 8, d = idx & (D - 1);
    out_ll[idx] = 0.0f;
    out_mean[idx] = 0.0f;
#pragma unroll
    for (int s = 0; s < S; ++s) out_s[((size_t)b * S + s) * D + d] = 0.0f;
  } else {
    int pos = atomicAdd(counter, 1);   // compiler aggregates per-wave (G12)
    list[pos] = idx;
  }
}

// ---------------- fused tail on compacted list (frozen R6/R7 numerics) ---
__global__ __launch_bounds__(256) void fused_tail(const float* __restrict__ headL,
                                                  const float* __restrict__ headMS,
                                                  const float* __restrict__ x,
                                                  const float* __restrict__ mask,
                                                  const int* __restrict__ list,
                                                  const int* __restrict__ counter,
                                                  float* __restrict__ out_ll,
                                                  float* __restrict__ out_s,
                                                  float* __restrict__ out_mean,
                                                  uint32_t kc0, uint32_t kc1,
                                                  uint32_t kn0, uint32_t kn1) {
  int i = blockIdx.x * 256 + threadIdx.x;
  if (i >= *counter) return;
  int idx = list[i];
  int b = idx >> 8, d = idx & (D - 1);
  const float* hpL = headL + (size_t)idx * K;        // row*2560 + d*10
  const float* hpM = headMS + (size_t)idx * (2 * K); // row*5120 + d*20
  float lg[K], mn[K], sc[K];
#pragma unroll
  for (int k = 0; k < K; ++k) { lg[k] = hpL[k]; mn[k] = hpM[k]; sc[k] = hpM[K + k]; }
  float q = 1.0f - mask[idx];          // == 1.0 exactly on this list
  float xu = x[idx] * q;
  float m = lg[0];
#pragma unroll
  for (int k = 1; k < K; ++k) m = fmaxf(m, lg[k]);
  float e[K];
  float sum = 0.0f;
#pragma unroll
  for (int k = 0; k < K; ++k) { e[k] = expf(lg[k] - m); sum += e[k]; }
  float lse = logf(sum);
  float a[K];
  float amax = -3.402823466e38f;
#pragma unroll
  for (int k = 0; k < K; ++k) {
    float z = (xu - mn[k]) / sc[k];
    float cll = -0.5f * z * z - logf(sc[k]) - 0.9189385332046727f;
    float lw = (lg[k] - m) - lse;
    a[k] = lw + cll;
    amax = fmaxf(amax, a[k]);
  }
  float s2 = 0.0f;
#pragma unroll
  for (int k = 0; k < K; ++k) s2 += expf(a[k] - amax);
  out_ll[idx] = (logf(s2) + amax) * q;
  float pm = 0.0f;
#pragma unroll
  for (int k = 0; k < K; ++k) pm += (e[k] / sum) * mn[k];
  out_mean[idx] = pm * q;
  float inv_e[K];
#pragma unroll
  for (int k = 0; k < K; ++k) inv_e[k] = 1.0f / e[k];
  for (int s = 0; s < S; ++s) {
    uint32_t t32 = (uint32_t)s * (uint32_t)ND + (uint32_t)idx;
    uint32_t base = t32 * (uint32_t)K;
    int best = 0;
    float rbest = 3.402823466e38f;
#pragma unroll
    for (int k = 0; k < K; ++k) {
      uint32_t bits = rb32(kc0, kc1, base + (uint32_t)k);
      float u = u01_from_bits(bits);
      float wv = -__log2f(u);              // hw v_log_f32; u=0 -> +inf (never wins)
      float r = wv * inv_e[k];
      if (r < rbest) { rbest = r; best = k; }  // first-min == reference first-max
    }
    uint32_t ebits = rb32(kn0, kn1, t32);
    float f = u01_from_bits(ebits);
    float r2 = f * 2.0f + (-0.99999994f);
    r2 = fmaxf(r2, -0.99999994f);
    float eps = 1.4142135623730951f * erfinv_f32(r2);
    out_s[((size_t)b * S + s) * D + d] = (mn[best] + sc[best] * eps) * q;
  }
}

// ---------------- launch ----------------
extern "C" void kernel_launch(void* const* d_in, const int* in_sizes, int n_in,
                              void* d_out, int out_size, void* d_ws, size_t ws_size,
                              hipStream_t stream) {
  const float* x    = (const float*)d_in[0];
  const float* mask = (const float*)d_in[1];
  const float* W_in = (const float*)d_in[2];
  const float* b_in = (const float*)d_in[3];
  const float* W1   = (const float*)d_in[4];
  const float* b1   = (const float*)d_in[5];
  const float* W2   = (const float*)d_in[6];
  const float* b2   = (const float*)d_in[7];
  const float* Wf   = (const float*)d_in[8];
  const float* bf   = (const float*)d_in[9];

  // workspace (unchanged footprint 149,946,372 B):
  //   [0, 41943040)            headL  B*2560 f32   (t alias: dead early)
  //   [41943040, 125829120)    headMS B*5120 f32
  //   [125829120, 134217728)   h      B*512  f32
  //   [134217728, 139460608)   wsgL / list alias
  //   [139460608, 149946368)   wms_h, wms_l
  //   [149946368, ...)         counter
  char* w = (char*)d_ws;
  float* headL  = (float*)w;                     // B*2560 f32
  float* headMS = (float*)(w + 41943040);        // B*5120 f32
  float* t      = headL;                         // alias: dead before fin
  float* h      = (float*)(w + 125829120);       // B*512 f32 (live through fin)
  float* wsgL   = (float*)(w + 134217728);       // 512*2560 f32 logit weights
  int*   list   = (int*)(w + 134217728);         // alias wsgL: ND ints (4 MB)
  short* wms_h  = (short*)(w + 139460608);       // 5120*512 bf16
  short* wms_l  = (short*)(w + 144703488);       // 5120*512 bf16
  int*   counter = (int*)(w + 149946368);        // 4 B

  float* out_ll   = (float*)d_out;               // (B,D)
  float* out_s    = out_ll + (size_t)ND;         // (B,S,D)
  float* out_mean = out_s + (size_t)ND * S;      // (B,D)

  wgatherL<<<dim3(NLOG / 256, 512), 256, 0, stream>>>(Wf, wsgL);
  wsplit_ms<<<dim3(NMS / 32, 512 / 32), 256, 0, stream>>>(Wf, wms_h, wms_l);

  dim3 gtr(H / 64, B / 64);  // (8, 64) = 512 blocks, 2 per CU, 8 waves/CU
  // trunk0 with fused prep: reads x,mask directly (x*mask inline)
  gemm_trunk<0, 0, 1><<<gtr, 256, 0, stream>>>(nullptr, W_in, b_in, nullptr, h,
                                               x, mask);
  for (int l = 0; l < NL; ++l) {
    gemm_trunk<1, 0, 0><<<gtr, 256, 0, stream>>>(h, W1 + (size_t)l * H * H,
                                                 b1 + (size_t)l * H, nullptr, t,
                                                 nullptr, nullptr);
    gemm_trunk<1, 1, 0><<<gtr, 256, 0, stream>>>(t, W2 + (size_t)l * H * H,
                                                 b2 + (size_t)l * H, h, h,
                                                 nullptr, nullptr);
  }

  // fused logits (fp32, x<20) + ms (MFMA, x>=20): 60x32 = 1920 blocks
  gemm_head<<<dim3(60, B / 128), 256, 0, stream>>>(h, wsgL, wms_h, wms_l, bf,
                                                   headL, headMS);

  // compaction (after gemm_head: list overwrites wsgL)
  hipMemsetAsync(counter, 0, 4, stream);
  compact_zero<<<ND / 256, 256, 0, stream>>>(mask, out_ll, out_s, out_mean,
                                             list, counter);

  uint32_t kc0, kc1, kn0, kn1;
  threefry2x32(0u, 1234u, 0u, 0u, kc0, kc1);
  threefry2x32(0u, 1234u, 0u, 1u, kn0, kn1);
  fused_tail<<<ND / 256, 256, 0, stream>>>(headL, headMS, x, mask, list, counter,
                                           out_ll, out_s, out_mean,
                                           kc0, kc1, kn0, kn1);
}

// Round 12
// 1130.243 us; speedup vs baseline: 1.1014x; 1.0084x over previous
//
#include <hip/hip_runtime.h>
#include <cstdint>

#define B 4096
#define D 256
#define H 512
#define K 10
#define NL 4
#define S 10
#define NOUT 30           // used head columns per d (3*K); tail C=64 unused
#define HEADW 94          // 3*K + C
#define ND (B*D)          // 1048576
#define NLOG 2560         // D*K   logits columns (exact fp32)
#define NMS  5120         // D*2K  means+scales columns (MFMA path)

typedef __bf16 bf16x8 __attribute__((ext_vector_type(8)));
typedef float  f32x16 __attribute__((ext_vector_type(16)));

// ---------------- threefry2x32 (JAX-exact) ----------------
__host__ __device__ inline void threefry2x32(uint32_t k0, uint32_t k1,
                                             uint32_t x0, uint32_t x1,
                                             uint32_t& o0, uint32_t& o1) {
  uint32_t ks2 = k0 ^ k1 ^ 0x1BD11BDAu;
#define TF_ROT(x, r) (((x) << (r)) | ((x) >> (32 - (r))))
#define TF_RND(r) { x0 += x1; x1 = TF_ROT(x1, r); x1 ^= x0; }
  x0 += k0; x1 += k1;
  TF_RND(13) TF_RND(15) TF_RND(26) TF_RND(6)
  x0 += k1; x1 += ks2 + 1u;
  TF_RND(17) TF_RND(29) TF_RND(16) TF_RND(24)
  x0 += ks2; x1 += k0 + 2u;
  TF_RND(13) TF_RND(15) TF_RND(26) TF_RND(6)
  x0 += k0; x1 += k1 + 3u;
  TF_RND(17) TF_RND(29) TF_RND(16) TF_RND(24)
  x0 += k1; x1 += ks2 + 4u;
  TF_RND(13) TF_RND(15) TF_RND(26) TF_RND(6)
  x0 += ks2; x1 += k0 + 5u;
  o0 = x0; o1 = x1;
#undef TF_RND
#undef TF_ROT
}

__device__ __forceinline__ uint32_t rb32(uint32_t k0, uint32_t k1, uint32_t idx) {
  uint32_t a, b;
  threefry2x32(k0, k1, 0u, idx, a, b);
  return a ^ b;
}

__device__ __forceinline__ float u01_from_bits(uint32_t bits) {
  return __uint_as_float((bits >> 9) | 0x3f800000u) - 1.0f;  // [0,1)
}

// XLA ErfInv32 (Giles single-precision polynomial)
__device__ __forceinline__ float erfinv_f32(float x) {
  float w = -log1pf(-x * x);
  float p;
  if (w < 5.0f) {
    w = w - 2.5f;
    p = 2.81022636e-08f;
    p = fmaf(p, w, 3.43273939e-07f);
    p = fmaf(p, w, -3.5233877e-06f);
    p = fmaf(p, w, -4.39150654e-06f);
    p = fmaf(p, w, 0.00021858087f);
    p = fmaf(p, w, -0.00125372503f);
    p = fmaf(p, w, -0.00417768164f);
    p = fmaf(p, w, 0.246640727f);
    p = fmaf(p, w, 1.50140941f);
  } else {
    w = sqrtf(w) - 3.0f;
    p = -0.000200214257f;
    p = fmaf(p, w, 0.000100950558f);
    p = fmaf(p, w, 0.00134934322f);
    p = fmaf(p, w, -0.00367342844f);
    p = fmaf(p, w, 0.00573950773f);
    p = fmaf(p, w, -0.0076224613f);
    p = fmaf(p, w, 0.00943887047f);
    p = fmaf(p, w, 1.00167406f);
    p = fmaf(p, w, 2.83297682f);
  }
  return p * x;
}

// ---------------- bf16 split helpers (R2-verified) ----------------
__device__ __forceinline__ unsigned short bf16_rne(float x) {
  uint32_t u = __float_as_uint(x);
  uint32_t r = u + 0x7fffu + ((u >> 16) & 1u);
  return (unsigned short)(r >> 16);
}

__device__ __forceinline__ void split2(float x, short& hi, short& lo) {
  unsigned short hb = bf16_rne(x);
  float hf = __uint_as_float((uint32_t)hb << 16);
  hi = (short)hb;
  lo = (short)bf16_rne(x - hf);
}

// ---------------- async global->LDS (16B/lane) ----------------
__device__ __forceinline__ void gload16(const void* g, void* l) {
  __builtin_amdgcn_global_load_lds(
      (const __attribute__((address_space(1))) void*)g,
      (__attribute__((address_space(3))) void*)l, 16, 0, 0);
}

// stage ROWS x 32 bf16 tile (row-major, 64B rows) from global [rows][512]
template <int ROWS>
__device__ __forceinline__ void stage_region(const short* __restrict__ g,
                                             short* l, int wid, int lane) {
#pragma unroll
  for (int c = wid; c < ROWS / 16; c += 4) {
    const short* gp = g + (size_t)(c * 16 + (lane >> 2)) * 512 + (lane & 3) * 8;
    gload16(gp, l + c * 512);
  }
}

// ---------------- logit weight gather: wsgL[k][c] = Wf[k][(c/10)*94 + c%10]
__global__ __launch_bounds__(256) void wgatherL(const float* __restrict__ Wf,
                                                float* __restrict__ wsgL) {
  int c = blockIdx.x * 256 + threadIdx.x;  // 0..2559
  int k = blockIdx.y;                      // 0..511
  int dd = c / K, j = c - dd * K;
  wsgL[(size_t)k * NLOG + c] = Wf[(size_t)k * (D * HEADW) + dd * HEADW + j];
}

// ---- MS weight transpose + 2-split: Wf[512][24064] -> wms hi/lo [5120][512]
__global__ __launch_bounds__(256) void wsplit_ms(const float* __restrict__ Wf,
                                                 short* __restrict__ whi,
                                                 short* __restrict__ wlo) {
  __shared__ float tile[32][33];
  int n0 = blockIdx.x * 32, k0 = blockIdx.y * 32;
  int tx = threadIdx.x & 31, ty = threadIdx.x >> 5;  // 32 x 8
#pragma unroll
  for (int r = 0; r < 4; ++r) {
    int k = k0 + ty + r * 8;
    int n = n0 + tx;
    int dd = n / 20, j = n - dd * 20;
    tile[ty + r * 8][tx] = Wf[(size_t)k * (D * HEADW) + dd * HEADW + 10 + j];
  }
  __syncthreads();
#pragma unroll
  for (int r = 0; r < 4; ++r) {
    int n = n0 + ty + r * 8;
    int k = k0 + tx;
    float v = tile[tx][ty + r * 8];
    short hb, lb;
    split2(v, hb, lb);
    whi[(size_t)n * 512 + k] = hb;
    wlo[(size_t)n * 512 + k] = lb;
  }
}

// ---------------- fp32 trunk GEMM (bit-identical chains to R1/R4) --------
// C(4096x512) = [relu?](A) @ W(512x512) + bias [+ res]
// 64x64 tile, BK=64 — the R6-measured config (best of 4 structural
// variants; 32x64, BK=32-dbuf, +swizzle all regressed).
// FP: fuse prep into trunk0's A-load (x*mask inline; wave-uniform branch).
// SPLIT: final layer also emits Ah/Al = bf16 2-split of h (same register
// value that is stored to C => operands bit-identical to the previous
// in-gemm_head split of reloaded h).
template <int RELU, int RES, int FP, int SPLIT>
__global__ __launch_bounds__(256) void gemm_trunk(const float* __restrict__ A,
                                                  const float* __restrict__ W,
                                                  const float* __restrict__ bias,
                                                  const float* res, float* C,
                                                  const float* __restrict__ xp,
                                                  const float* __restrict__ mp,
                                                  short* __restrict__ Ah,
                                                  short* __restrict__ Al) {
  __shared__ float As[64 * 68];  // [k][m], stride 68 (272B, 16B-aligned)
  __shared__ float Ws[64 * 64];  // [k][n], stride 64
  const int tid = threadIdx.x;
  const int lane = tid & 63, wid = tid >> 6;
  const int tx = tid & 15, ty = tid >> 4;
  const int bm = blockIdx.y * 64, bn = blockIdx.x * 64;
  const int ls = tid & 15, lm = tid >> 4;  // A-load: k-slot(16), row(16)

  float acc[4][4] = {};

  for (int k0 = 0; k0 < H; k0 += 64) {
#pragma unroll
    for (int c = wid; c < 16; c += 4) {
      gload16(W + (size_t)(k0 + c * 4 + (lane >> 4)) * H + bn + (lane & 15) * 4,
              Ws + c * 256 + lane * 4);
    }
#pragma unroll
    for (int r = 0; r < 4; ++r) {
      int m = lm + 16 * r;
      float4 f;
      if (FP) {
        int c = k0 + 4 * ls;               // 4-aligned; never straddles D
        const int brow = bm + m;
        if (c < D) {
          float4 xv = *(const float4*)(xp + (size_t)brow * D + c);
          float4 mv = *(const float4*)(mp + (size_t)brow * D + c);
          f.x = xv.x * mv.x; f.y = xv.y * mv.y;
          f.z = xv.z * mv.z; f.w = xv.w * mv.w;
        } else {
          f = *(const float4*)(mp + (size_t)brow * D + (c - D));
        }
      } else {
        f = *(const float4*)(A + (size_t)(bm + m) * H + k0 + 4 * ls);
      }
      if (RELU) {
        f.x = fmaxf(f.x, 0.0f); f.y = fmaxf(f.y, 0.0f);
        f.z = fmaxf(f.z, 0.0f); f.w = fmaxf(f.w, 0.0f);
      }
      As[(4 * ls + 0) * 68 + m] = f.x;
      As[(4 * ls + 1) * 68 + m] = f.y;
      As[(4 * ls + 2) * 68 + m] = f.z;
      As[(4 * ls + 3) * 68 + m] = f.w;
    }
    __syncthreads();
#pragma unroll
    for (int kk = 0; kk < 64; ++kk) {
      float4 a4 = *(const float4*)(As + kk * 68 + ty * 4);
      float4 b4 = *(const float4*)(Ws + kk * 64 + tx * 4);
      float a[4] = {a4.x, a4.y, a4.z, a4.w};
      float b[4] = {b4.x, b4.y, b4.z, b4.w};
#pragma unroll
      for (int i = 0; i < 4; ++i)
#pragma unroll
        for (int j = 0; j < 4; ++j) acc[i][j] = fmaf(a[i], b[j], acc[i][j]);
    }
    __syncthreads();
  }
#pragma unroll
  for (int i = 0; i < 4; ++i) {
    int row = bm + ty * 4 + i;
    float v[4];
#pragma unroll
    for (int j = 0; j < 4; ++j) {
      int col = bn + tx * 4 + j;
      v[j] = acc[i][j] + bias[col];
      if (RES) v[j] = res[(size_t)row * H + col] + v[j];  // same order as R1
      C[(size_t)row * H + col] = v[j];
    }
    if (SPLIT) {
      short4 h4, l4;
      split2(v[0], h4.x, l4.x); split2(v[1], h4.y, l4.y);
      split2(v[2], h4.z, l4.z); split2(v[3], h4.w, l4.w);
      *(short4*)(Ah + (size_t)row * H + bn + tx * 4) = h4;
      *(short4*)(Al + (size_t)row * H + bn + tx * 4) = l4;
    }
  }
}

// ---------------- FUSED head GEMM: logits (fp32, exact) + ms (MFMA) ------
// R6-measured structure.  Round 12: ms path A-staging is now pure DMA —
// stage_region on pre-split Ah/Al (written by the final trunk), replacing
// the per-block float4-load + split2 + LDS-write chain that redid the
// same A split 40x (once per ms column block).  LDS layout identical
// (c*512 + lane*8 == (c*16+lane/4)*32 + (lane%4)*8), operands
// bit-identical.  Logits path untouched.
__global__ __launch_bounds__(256) void gemm_head(const float* __restrict__ A,
                                                 const float* __restrict__ Wg,
                                                 const short* __restrict__ Bh,
                                                 const short* __restrict__ Bl,
                                                 const short* __restrict__ Ah,
                                                 const short* __restrict__ Al,
                                                 const float* __restrict__ bf,
                                                 float* __restrict__ headL,
                                                 float* __restrict__ headMS) {
  __shared__ __align__(16) float smem[8448];  // 33792 B shared by both paths
  const int tid = threadIdx.x;
  const int lane = tid & 63, wid = tid >> 6;
  const int bm = blockIdx.y * 128;

  if (blockIdx.x < 20) {
    // ---------- logits path (exact fp32; frozen fmaf chains) ----------
    float* As = smem;          // 32*136
    float* Ws = smem + 4352;   // 32*128
    const int tx = tid & 15, ty = tid >> 4;
    const int bn = blockIdx.x * 128;
    const int ls = tid & 7, lm = tid >> 3;

    float acc[8][8] = {};

    for (int k0 = 0; k0 < H; k0 += 32) {
#pragma unroll
      for (int c = wid; c < 16; c += 4) {
        gload16(Wg + (size_t)(k0 + c * 2 + (lane >> 5)) * NLOG + bn + (lane & 31) * 4,
                Ws + c * 256 + lane * 4);
      }
#pragma unroll
      for (int r = 0; r < 4; ++r) {
        int m = lm + 32 * r;
        float4 f = *(const float4*)(A + (size_t)(bm + m) * H + k0 + 4 * ls);
        As[(4 * ls + 0) * 136 + m] = f.x;
        As[(4 * ls + 1) * 136 + m] = f.y;
        As[(4 * ls + 2) * 136 + m] = f.z;
        As[(4 * ls + 3) * 136 + m] = f.w;
      }
      __syncthreads();
#pragma unroll
      for (int kk = 0; kk < 32; ++kk) {
        float a[8], b[8];
        *(float4*)(a + 0) = *(const float4*)(As + kk * 136 + ty * 8);
        *(float4*)(a + 4) = *(const float4*)(As + kk * 136 + ty * 8 + 4);
        *(float4*)(b + 0) = *(const float4*)(Ws + kk * 128 + tx * 8);
        *(float4*)(b + 4) = *(const float4*)(Ws + kk * 128 + tx * 8 + 4);
#pragma unroll
        for (int i = 0; i < 8; ++i)
#pragma unroll
          for (int j = 0; j < 8; ++j) acc[i][j] = fmaf(a[i], b[j], acc[i][j]);
      }
      __syncthreads();
    }
    // epilogue: same values (acc + bias), vectorized contiguous stores
    float bias[8];
#pragma unroll
    for (int j = 0; j < 8; ++j) {
      int c = bn + tx * 8 + j;
      int dd = c / K, jj = c - dd * K;
      bias[j] = bf[dd * HEADW + jj];
    }
#pragma unroll
    for (int i = 0; i < 8; ++i) {
      int row = bm + ty * 8 + i;
      float4 v0, v1;
      v0.x = acc[i][0] + bias[0]; v0.y = acc[i][1] + bias[1];
      v0.z = acc[i][2] + bias[2]; v0.w = acc[i][3] + bias[3];
      v1.x = acc[i][4] + bias[4]; v1.y = acc[i][5] + bias[5];
      v1.z = acc[i][6] + bias[6]; v1.w = acc[i][7] + bias[7];
      float* dst = headL + (size_t)row * NLOG + bn + tx * 8;
      *(float4*)dst = v0;
      *(float4*)(dst + 4) = v1;
    }
  } else {
    // ---------- ms path (MFMA; pure-DMA staging, frozen fragment code) --
    short* lds = (short*)smem;   // uses 16384 B
    const int wm = wid >> 1, wn = wid & 1;
    const int bn = (blockIdx.x - 20) * 128;

    short* ldsAh = lds;
    short* ldsAl = lds + 4096;
    short* ldsBh = lds + 8192;
    short* ldsBl = lds + 12288;

    const short* gBh = Bh + (size_t)bn * 512;
    const short* gBl = Bl + (size_t)bn * 512;
    const short* gAh = Ah + (size_t)bm * 512;
    const short* gAl = Al + (size_t)bm * 512;

    f32x16 acc[2][2];
#pragma unroll
    for (int mt = 0; mt < 2; ++mt)
#pragma unroll
      for (int nt = 0; nt < 2; ++nt)
#pragma unroll
        for (int i = 0; i < 16; ++i) acc[mt][nt][i] = 0.0f;

    for (int k0 = 0; k0 < 512; k0 += 32) {
      stage_region<128>(gBh + k0, ldsBh, wid, lane);
      stage_region<128>(gBl + k0, ldsBl, wid, lane);
      stage_region<128>(gAh + k0, ldsAh, wid, lane);
      stage_region<128>(gAl + k0, ldsAl, wid, lane);
      __syncthreads();
#pragma unroll
      for (int sub = 0; sub < 2; ++sub) {
        bf16x8 ah[2], al[2], bh[2], bl[2];
#pragma unroll
        for (int mt = 0; mt < 2; ++mt) {
          int r = wm * 64 + mt * 32 + (lane & 31);
          int off = r * 32 + sub * 16 + (lane >> 5) * 8;
          ah[mt] = *(const bf16x8*)(ldsAh + off);
          al[mt] = *(const bf16x8*)(ldsAl + off);
        }
#pragma unroll
        for (int nt = 0; nt < 2; ++nt) {
          int r = wn * 64 + nt * 32 + (lane & 31);
          int off = r * 32 + sub * 16 + (lane >> 5) * 8;
          bh[nt] = *(const bf16x8*)(ldsBh + off);
          bl[nt] = *(const bf16x8*)(ldsBl + off);
        }
#pragma unroll
        for (int mt = 0; mt < 2; ++mt)
#pragma unroll
          for (int nt = 0; nt < 2; ++nt) {
            acc[mt][nt] = __builtin_amdgcn_mfma_f32_32x32x16_bf16(ah[mt], bh[nt], acc[mt][nt], 0, 0, 0);
            acc[mt][nt] = __builtin_amdgcn_mfma_f32_32x32x16_bf16(ah[mt], bl[nt], acc[mt][nt], 0, 0, 0);
            acc[mt][nt] = __builtin_amdgcn_mfma_f32_32x32x16_bf16(al[mt], bh[nt], acc[mt][nt], 0, 0, 0);
          }
      }
      __syncthreads();
    }

#pragma unroll
    for (int mt = 0; mt < 2; ++mt)
#pragma unroll
      for (int nt = 0; nt < 2; ++nt) {
        int col = bn + wn * 64 + nt * 32 + (lane & 31);   // 0..5119
        int rbase = bm + wm * 64 + mt * 32 + 4 * (lane >> 5);
        int dd = col / 20, j = col - dd * 20;
#pragma unroll
        for (int reg = 0; reg < 16; ++reg) {
          int row = rbase + (reg & 3) + 8 * (reg >> 2);
          float v = acc[mt][nt][reg] + bf[dd * HEADW + 10 + j];
          if (j >= 10) v = (fmaxf(v, 0.0f) + log1pf(expf(-fabsf(v)))) + 0.001f;
          headMS[(size_t)row * NMS + col] = v;   // contiguous cols, no RMW mix
        }
      }
  }
}

// ---------------- tail compaction -----------------------------------------
__global__ __launch_bounds__(256) void compact_zero(const float* __restrict__ mask,
                                                    float* __restrict__ out_ll,
                                                    float* __restrict__ out_s,
                                                    float* __restrict__ out_mean,
                                                    int* __restrict__ list,
                                                    int* __restrict__ counter) {
  int idx = blockIdx.x * 256 + threadIdx.x;
  if (idx >= ND) return;
  if (mask[idx] != 0.0f) {   // observed -> q = 0 -> outputs all zero
    int b = idx >> 8, d = idx & (D - 1);
    out_ll[idx] = 0.0f;
    out_mean[idx] = 0.0f;
#pragma unroll
    for (int s = 0; s < S; ++s) out_s[((size_t)b * S + s) * D + d] = 0.0f;
  } else {
    int pos = atomicAdd(counter, 1);   // compiler aggregates per-wave (G12)
    list[pos] = idx;
  }
}

// ---------------- fused tail on compacted list (frozen R6/R7 numerics) ---
__global__ __launch_bounds__(256) void fused_tail(const float* __restrict__ headL,
                                                  const float* __restrict__ headMS,
                                                  const float* __restrict__ x,
                                                  const float* __restrict__ mask,
                                                  const int* __restrict__ list,
                                                  const int* __restrict__ counter,
                                                  float* __restrict__ out_ll,
                                                  float* __restrict__ out_s,
                                                  float* __restrict__ out_mean,
                                                  uint32_t kc0, uint32_t kc1,
                                                  uint32_t kn0, uint32_t kn1) {
  int i = blockIdx.x * 256 + threadIdx.x;
  if (i >= *counter) return;
  int idx = list[i];
  int b = idx >> 8, d = idx & (D - 1);
  const float* hpL = headL + (size_t)idx * K;        // row*2560 + d*10
  const float* hpM = headMS + (size_t)idx * (2 * K); // row*5120 + d*20
  float lg[K], mn[K], sc[K];
#pragma unroll
  for (int k = 0; k < K; ++k) { lg[k] = hpL[k]; mn[k] = hpM[k]; sc[k] = hpM[K + k]; }
  float q = 1.0f - mask[idx];          // == 1.0 exactly on this list
  float xu = x[idx] * q;
  float m = lg[0];
#pragma unroll
  for (int k = 1; k < K; ++k) m = fmaxf(m, lg[k]);
  float e[K];
  float sum = 0.0f;
#pragma unroll
  for (int k = 0; k < K; ++k) { e[k] = expf(lg[k] - m); sum += e[k]; }
  float lse = logf(sum);
  float a[K];
  float amax = -3.402823466e38f;
#pragma unroll
  for (int k = 0; k < K; ++k) {
    float z = (xu - mn[k]) / sc[k];
    float cll = -0.5f * z * z - logf(sc[k]) - 0.9189385332046727f;
    float lw = (lg[k] - m) - lse;
    a[k] = lw + cll;
    amax = fmaxf(amax, a[k]);
  }
  float s2 = 0.0f;
#pragma unroll
  for (int k = 0; k < K; ++k) s2 += expf(a[k] - amax);
  out_ll[idx] = (logf(s2) + amax) * q;
  float pm = 0.0f;
#pragma unroll
  for (int k = 0; k < K; ++k) pm += (e[k] / sum) * mn[k];
  out_mean[idx] = pm * q;
  float inv_e[K];
#pragma unroll
  for (int k = 0; k < K; ++k) inv_e[k] = 1.0f / e[k];
  for (int s = 0; s < S; ++s) {
    uint32_t t32 = (uint32_t)s * (uint32_t)ND + (uint32_t)idx;
    uint32_t base = t32 * (uint32_t)K;
    int best = 0;
    float rbest = 3.402823466e38f;
#pragma unroll
    for (int k = 0; k < K; ++k) {
      uint32_t bits = rb32(kc0, kc1, base + (uint32_t)k);
      float u = u01_from_bits(bits);
      float wv = -__log2f(u);              // hw v_log_f32; u=0 -> +inf (never wins)
      float r = wv * inv_e[k];
      if (r < rbest) { rbest = r; best = k; }  // first-min == reference first-max
    }
    uint32_t ebits = rb32(kn0, kn1, t32);
    float f = u01_from_bits(ebits);
    float r2 = f * 2.0f + (-0.99999994f);
    r2 = fmaxf(r2, -0.99999994f);
    float eps = 1.4142135623730951f * erfinv_f32(r2);
    out_s[((size_t)b * S + s) * D + d] = (mn[best] + sc[best] * eps) * q;
  }
}

// ---------------- launch ----------------
extern "C" void kernel_launch(void* const* d_in, const int* in_sizes, int n_in,
                              void* d_out, int out_size, void* d_ws, size_t ws_size,
                              hipStream_t stream) {
  const float* x    = (const float*)d_in[0];
  const float* mask = (const float*)d_in[1];
  const float* W_in = (const float*)d_in[2];
  const float* b_in = (const float*)d_in[3];
  const float* W1   = (const float*)d_in[4];
  const float* b1   = (const float*)d_in[5];
  const float* W2   = (const float*)d_in[6];
  const float* b2   = (const float*)d_in[7];
  const float* Wf   = (const float*)d_in[8];
  const float* bf   = (const float*)d_in[9];

  // workspace (unchanged footprint 149,946,372 B):
  //   [0, 41943040)            headL  B*2560 f32   (t alias: dead early)
  //   [41943040, 125829120)    headMS B*5120 f32
  //   [125829120, 134217728)   h      B*512  f32
  //   [134217728, 139460608)   wsgL / list alias
  //   [139460608, 149946368)   wms_h, wms_l
  //   [149946368, ...)         counter
  char* w = (char*)d_ws;
  float* headL  = (float*)w;                     // B*2560 f32
  float* headMS = (float*)(w + 41943040);        // B*5120 f32
  float* t      = headL;                         // alias: dead before fin
  float* h      = (float*)(w + 125829120);       // B*512 f32 (live through fin)
  float* wsgL   = (float*)(w + 134217728);       // 512*2560 f32 logit weights
  int*   list   = (int*)(w + 134217728);         // alias wsgL: ND ints (4 MB)
  short* wms_h  = (short*)(w + 139460608);       // 5120*512 bf16
  short* wms_l  = (short*)(w + 144703488);       // 5120*512 bf16
  int*   counter = (int*)(w + 149946368);        // 4 B

  float* out_ll   = (float*)d_out;               // (B,D)
  float* out_s    = out_ll + (size_t)ND;         // (B,S,D)
  float* out_mean = out_s + (size_t)ND * S;      // (B,D)

  // Ah/Al scratch lives in the out_s region of d_out (41.9 MB >> 8.4 MB):
  // written by the final trunk, read by gemm_head, overwritten by
  // compact_zero strictly later in-stream.  No workspace growth.
  short* Ah = (short*)out_s;                     // B*512 bf16 (4 MB)
  short* Al = Ah + (size_t)B * H;                // B*512 bf16 (4 MB)

  wgatherL<<<dim3(NLOG / 256, 512), 256, 0, stream>>>(Wf, wsgL);
  wsplit_ms<<<dim3(NMS / 32, 512 / 32), 256, 0, stream>>>(Wf, wms_h, wms_l);

  dim3 gtr(H / 64, B / 64);  // (8, 64) = 512 blocks, 2 per CU, 8 waves/CU
  // trunk0 with fused prep: reads x,mask directly (x*mask inline)
  gemm_trunk<0, 0, 1, 0><<<gtr, 256, 0, stream>>>(nullptr, W_in, b_in, nullptr,
                                                  h, x, mask, nullptr, nullptr);
  for (int l = 0; l < NL - 1; ++l) {
    gemm_trunk<1, 0, 0, 0><<<gtr, 256, 0, stream>>>(h, W1 + (size_t)l * H * H,
                                                    b1 + (size_t)l * H, nullptr,
                                                    t, nullptr, nullptr,
                                                    nullptr, nullptr);
    gemm_trunk<1, 1, 0, 0><<<gtr, 256, 0, stream>>>(t, W2 + (size_t)l * H * H,
                                                    b2 + (size_t)l * H, h, h,
                                                    nullptr, nullptr,
                                                    nullptr, nullptr);
  }
  // final layer: RES epilogue also emits the bf16 2-split of h (Ah/Al)
  gemm_trunk<1, 0, 0, 0><<<gtr, 256, 0, stream>>>(h, W1 + (size_t)3 * H * H,
                                                  b1 + (size_t)3 * H, nullptr,
                                                  t, nullptr, nullptr,
                                                  nullptr, nullptr);
  gemm_trunk<1, 1, 0, 1><<<gtr, 256, 0, stream>>>(t, W2 + (size_t)3 * H * H,
                                                  b2 + (size_t)3 * H, h, h,
                                                  nullptr, nullptr, Ah, Al);

  // fused logits (fp32, x<20) + ms (MFMA, x>=20): 60x32 = 1920 blocks
  gemm_head<<<dim3(60, B / 128), 256, 0, stream>>>(h, wsgL, wms_h, wms_l,
                                                   Ah, Al, bf, headL, headMS);

  // compaction (after gemm_head: list overwrites wsgL)
  hipMemsetAsync(counter, 0, 4, stream);
  compact_zero<<<ND / 256, 256, 0, stream>>>(mask, out_ll, out_s, out_mean,
                                             list, counter);

  uint32_t kc0, kc1, kn0, kn1;
  threefry2x32(0u, 1234u, 0u, 0u, kc0, kc1);
  threefry2x32(0u, 1234u, 0u, 1u, kn0, kn1);
  fused_tail<<<ND / 256, 256, 0, stream>>>(headL, headMS, x, mask, list, counter,
                                           out_ll, out_s, out_mean,
                                           kc0, kc1, kn0, kn1);
}